// Round 3
// baseline (800.014 us; speedup 1.0000x reference)
//
#include <hip/hip_runtime.h>
#include <hip/hip_bf16.h>
#include <stdint.h>

#define TOK   16384
#define DDIM  1024
#define NEXP  8

#define BM 128
#define BN 128
#define BK 32

typedef __attribute__((ext_vector_type(8))) short  short8;
typedef __attribute__((ext_vector_type(4))) float  floatx4;

// round-to-nearest-even f32 -> bf16 (normal-range data; no NaN path needed)
static __device__ __forceinline__ unsigned int bf16_rne(float f) {
  unsigned int u = __builtin_bit_cast(unsigned int, f);
  return (u + 0x7fffu + ((u >> 16) & 1u)) >> 16;
}
static __device__ __forceinline__ unsigned int pack_bf16x2(float a, float b) {
  return bf16_rne(a) | (bf16_rne(b) << 16);
}

// ---------------------------------------------------------------------------
// Kernel 1: fp32 gate. One wave per token. w[t][8] = renormalized thresholded
// softmax(x @ gate_w + gate_b). fp32 throughout: selection decisions (>= 0.1)
// must not flip vs the fp32 reference.
// ---------------------------------------------------------------------------
__global__ __launch_bounds__(256) void gate_kernel(
    const float* __restrict__ x, const float* __restrict__ gw,
    const float* __restrict__ gb, float* __restrict__ wout) {
  int wave = threadIdx.x >> 6;
  int lane = threadIdx.x & 63;
  int t = blockIdx.x * 4 + wave;
  const float* xr = x + (size_t)t * DDIM;

  float acc[8];
#pragma unroll
  for (int e = 0; e < 8; ++e) acc[e] = 0.f;

#pragma unroll
  for (int i = 0; i < DDIM / 64; ++i) {
    int k = lane + 64 * i;
    float xv = xr[k];
    const float4* g = (const float4*)(gw + (size_t)k * 8);
    float4 g0 = g[0];
    float4 g1 = g[1];
    acc[0] += xv * g0.x; acc[1] += xv * g0.y;
    acc[2] += xv * g0.z; acc[3] += xv * g0.w;
    acc[4] += xv * g1.x; acc[5] += xv * g1.y;
    acc[6] += xv * g1.z; acc[7] += xv * g1.w;
  }
#pragma unroll
  for (int off = 32; off > 0; off >>= 1) {
#pragma unroll
    for (int e = 0; e < 8; ++e) acc[e] += __shfl_xor(acc[e], off, 64);
  }
  if (lane == 0) {
    float logit[8];
    float m = -1e30f;
#pragma unroll
    for (int e = 0; e < 8; ++e) {
      logit[e] = acc[e] + gb[e];
      m = fmaxf(m, logit[e]);
    }
    float p[8], s = 0.f;
#pragma unroll
    for (int e = 0; e < 8; ++e) { p[e] = expf(logit[e] - m); s += p[e]; }
    float wv[8], wsum = 0.f;
#pragma unroll
    for (int e = 0; e < 8; ++e) {
      float pr = p[e] / s;
      wv[e] = (pr >= 0.1f) ? pr : 0.f;
      wsum += wv[e];
    }
    float invw = (wsum == 0.f) ? 1.f : (1.f / wsum);
#pragma unroll
    for (int e = 0; e < 8; ++e) wout[(size_t)t * 8 + e] = wv[e] * invw;
  }
}

// ---------------------------------------------------------------------------
// Kernel 2: x fp32 [t][k] -> Xt bf16 chunk-tiled [t/16][k/32][16][32].
// Each 1 KB chunk (16 token-rows x 32 k) is contiguous -> GEMM DMA loads are
// fully coalesced 1 KB wave transactions.
// ---------------------------------------------------------------------------
__global__ __launch_bounds__(256) void prep_x(
    const float* __restrict__ x, unsigned short* __restrict__ xt) {
  int g  = blockIdx.x * 256 + threadIdx.x;
  int k8 = g & 127;   // 8-element k segment
  int t  = g >> 7;
  const float* src = x + (size_t)t * DDIM + k8 * 8;
  float4 v0 = *(const float4*)src;
  float4 v1 = *(const float4*)(src + 4);
  uint4 pk;
  pk.x = pack_bf16x2(v0.x, v0.y); pk.y = pack_bf16x2(v0.z, v0.w);
  pk.z = pack_bf16x2(v1.x, v1.y); pk.w = pack_bf16x2(v1.z, v1.w);
  int m16 = t >> 4, r = t & 15, k32 = k8 >> 2, kc = (k8 & 3) * 8;
  *(uint4*)(xt + (((size_t)m16 * 32 + k32) << 9) + r * 32 + kc) = pk;
}

// ---------------------------------------------------------------------------
// Kernel 3: expert_w fp32 [e][k][d] -> Bt bf16 chunk-tiled [e][d/16][k/32][16][32]
// (transpose via LDS 32x32 tile so k becomes the contiguous frag dimension).
// ---------------------------------------------------------------------------
__global__ __launch_bounds__(256) void prep_w(
    const float* __restrict__ ew, unsigned short* __restrict__ bt) {
  __shared__ float tile[32][33];
  int e  = blockIdx.z;
  int k0 = blockIdx.y * 32;
  int d0 = blockIdx.x * 32;
  int c4 = threadIdx.x & 7;
  int r  = threadIdx.x >> 3;

  const float* src = ew + ((size_t)e << 20) + (size_t)(k0 + r) * DDIM + d0 + c4 * 4;
  float4 v = *(const float4*)src;
  tile[r][c4 * 4 + 0] = v.x;
  tile[r][c4 * 4 + 1] = v.y;
  tile[r][c4 * 4 + 2] = v.z;
  tile[r][c4 * 4 + 3] = v.w;
  __syncthreads();

  uint2 pk;
  pk.x = pack_bf16x2(tile[c4 * 4 + 0][r], tile[c4 * 4 + 1][r]);
  pk.y = pack_bf16x2(tile[c4 * 4 + 2][r], tile[c4 * 4 + 3][r]);
  int d   = d0 + r;                 // output row (d), cols k0+c4*4..+3
  int d16 = d >> 4, r16 = d & 15, k32 = k0 >> 5, kc = c4 * 4;
  *(uint2*)(bt + ((((size_t)e * 64 + d16) * 32 + k32) << 9) + r16 * 32 + kc) = pk;
}

// ---------------------------------------------------------------------------
// Kernel 4: MoE GEMM, m97 structure. Pure bf16 K-loop: both tiles staged by
// global_load_lds width-16 from chunk-tiled workspace; zero VALU convert.
// Gate weight applied at expert boundaries: outac += w[t,e] * acc; acc = 0.
// Bias folded into epilogue.
// ---------------------------------------------------------------------------
__global__ __launch_bounds__(256) void moe_gemm(
    const unsigned short* __restrict__ xt,  // [1024][32][16][32] bf16
    const float* __restrict__ w,            // [16384][8]
    const unsigned short* __restrict__ bt,  // [8][64][32][16][32] bf16
    const float* __restrict__ eb, float* __restrict__ out) {
  __shared__ unsigned short As[8 * 512];  // 8 chunks x 1 KB
  __shared__ unsigned short Bs[8 * 512];

  int tid  = threadIdx.x;
  int wave = tid >> 6;
  int lane = tid & 63;
  int bn0  = blockIdx.x * BN;   // column tile (x fastest: 8 col-blocks share A slice in L2)
  int bm0  = blockIdx.y * BM;   // token tile
  int wm   = (wave >> 1) * 64;
  int wn   = (wave & 1) * 64;
  int fr   = lane & 15;
  int q8   = (lane >> 4) * 8;
  int cr0  = (lane >> 4) * 4;

  const int bm16 = bm0 >> 4;  // global m-chunk base
  const int bn16 = bn0 >> 4;  // n-chunk base within expert

  floatx4 acc[4][4], outac[4][4];
#pragma unroll
  for (int mi = 0; mi < 4; ++mi)
#pragma unroll
    for (int ni = 0; ni < 4; ++ni) { acc[mi][ni] = (floatx4)0.f; outac[mi][ni] = (floatx4)0.f; }

  for (int e = 0; e < 8; ++e) {
    const unsigned short* bbase = bt + (((size_t)e * 2048) << 9);
    for (int kt = 0; kt < 32; ++kt) {
      __syncthreads();  // previous iteration's frag reads complete
#pragma unroll
      for (int j = 0; j < 2; ++j) {
        int c = wave * 2 + j;
        const unsigned short* gpa =
            xt + ((((size_t)(bm16 + c)) * 32 + kt) << 9) + lane * 8;
        __builtin_amdgcn_global_load_lds(
            (const __attribute__((address_space(1))) unsigned int*)gpa,
            (__attribute__((address_space(3))) unsigned int*)(As + c * 512), 16, 0, 0);
        const unsigned short* gpb =
            bbase + ((((size_t)(bn16 + c)) * 32 + kt) << 9) + lane * 8;
        __builtin_amdgcn_global_load_lds(
            (const __attribute__((address_space(1))) unsigned int*)gpb,
            (__attribute__((address_space(3))) unsigned int*)(Bs + c * 512), 16, 0, 0);
      }
      __syncthreads();  // staged data visible

      short8 af[4], bfr[4];
#pragma unroll
      for (int mi = 0; mi < 4; ++mi)
        af[mi] = *(const short8*)&As[((((wm >> 4) + mi)) << 9) + fr * 32 + q8];
#pragma unroll
      for (int ni = 0; ni < 4; ++ni)
        bfr[ni] = *(const short8*)&Bs[((((wn >> 4) + ni)) << 9) + fr * 32 + q8];
#pragma unroll
      for (int mi = 0; mi < 4; ++mi)
#pragma unroll
        for (int ni = 0; ni < 4; ++ni)
          acc[mi][ni] = __builtin_amdgcn_mfma_f32_16x16x32_bf16(
              af[mi], bfr[ni], acc[mi][ni], 0, 0, 0);
    }
    // expert boundary: fold gate weight into output accumulator
#pragma unroll
    for (int mi = 0; mi < 4; ++mi)
#pragma unroll
      for (int r = 0; r < 4; ++r) {
        int t = bm0 + wm + mi * 16 + cr0 + r;
        float wv = w[(size_t)t * 8 + e];
#pragma unroll
        for (int ni = 0; ni < 4; ++ni) {
          outac[mi][ni][r] += wv * acc[mi][ni][r];
          acc[mi][ni][r] = 0.f;
        }
      }
  }

  // ---- epilogue: C layout col=lane&15, row=(lane>>4)*4+reg; weighted bias
  float ebv[8][4];
#pragma unroll
  for (int e = 0; e < 8; ++e)
#pragma unroll
    for (int ni = 0; ni < 4; ++ni)
      ebv[e][ni] = eb[(size_t)e * DDIM + bn0 + wn + ni * 16 + fr];

#pragma unroll
  for (int mi = 0; mi < 4; ++mi) {
#pragma unroll
    for (int r = 0; r < 4; ++r) {
      int t = bm0 + wm + mi * 16 + cr0 + r;
      const float4* wp = (const float4*)(w + (size_t)t * 8);
      float4 w0 = wp[0];
      float4 w1 = wp[1];
      float* orow = out + (size_t)t * DDIM + bn0 + wn + fr;
#pragma unroll
      for (int ni = 0; ni < 4; ++ni) {
        float bias = w0.x * ebv[0][ni] + w0.y * ebv[1][ni] +
                     w0.z * ebv[2][ni] + w0.w * ebv[3][ni] +
                     w1.x * ebv[4][ni] + w1.y * ebv[5][ni] +
                     w1.z * ebv[6][ni] + w1.w * ebv[7][ni];
        orow[ni * 16] = outac[mi][ni][r] + bias;
      }
    }
  }
}

// ---------------------------------------------------------------------------
extern "C" void kernel_launch(void* const* d_in, const int* in_sizes, int n_in,
                              void* d_out, int out_size, void* d_ws, size_t ws_size,
                              hipStream_t stream) {
  const float* x  = (const float*)d_in[0];   // [4,4096,1024]
  const float* gw = (const float*)d_in[1];   // [1024,8]
  const float* gb = (const float*)d_in[2];   // [8]
  const float* ew = (const float*)d_in[3];   // [8,1024,1024]
  const float* eb = (const float*)d_in[4];   // [8,1024]
  float* out = (float*)d_out;

  // ws: w[16384*8] fp32 (512 KB) | Xt bf16 chunk-tiled (32 MB) | Bt bf16 (16 MB)
  float* wbuf = (float*)d_ws;
  unsigned short* xt = (unsigned short*)((char*)d_ws + (size_t)TOK * 8 * 4);
  unsigned short* bt = xt + (size_t)TOK * DDIM;

  gate_kernel<<<TOK / 4, 256, 0, stream>>>(x, gw, gb, wbuf);
  prep_x<<<(TOK * (DDIM / 8)) / 256, 256, 0, stream>>>(x, xt);
  prep_w<<<dim3(DDIM / 32, DDIM / 32, NEXP), 256, 0, stream>>>(ew, bt);
  moe_gemm<<<dim3(DDIM / BN, TOK / BM), 256, 0, stream>>>(xt, wbuf, bt, eb, out);
}

// Round 4
// 540.498 us; speedup vs baseline: 1.4801x; 1.4801x over previous
//
#include <hip/hip_runtime.h>
#include <stdint.h>

#define TOK   16384
#define DDIM  1024
#define NEXP  8
#define BM    128
#define BN    128
#define WEPS  1e-5f

typedef __attribute__((ext_vector_type(8))) short  short8;
typedef __attribute__((ext_vector_type(4))) float  floatx4;

// round-to-nearest-even f32 -> bf16 (normal-range data; no NaN path needed)
static __device__ __forceinline__ unsigned int bf16_rne(float f) {
  unsigned int u = __builtin_bit_cast(unsigned int, f);
  return (u + 0x7fffu + ((u >> 16) & 1u)) >> 16;
}
static __device__ __forceinline__ unsigned int pack2(float a, float b) {
  return bf16_rne(a) | (bf16_rne(b) << 16);
}

// ---------------------------------------------------------------------------
// Kernel 1: fused gate + x->bf16 prep. One wave per token.
//  (a) w[t][8] = renormalized thresholded softmax(x@gw+gb), fp32 (selection
//      decisions must match fp32 reference).
//  (b) writes Xt bf16 chunk-tiled [t/16][k/32][16][32] with XOR bank swizzle:
//      element (r,k) at r*32 + (k ^ (((r>>1)&3)*8)) -> GEMM ds_read_b128 frag
//      reads are 2-way bank aliased (free), not 8-way.
// ---------------------------------------------------------------------------
__global__ __launch_bounds__(256) void gate_prep(
    const float* __restrict__ x, const float* __restrict__ gw,
    const float* __restrict__ gb, float* __restrict__ wout,
    unsigned short* __restrict__ xt) {
  int wave = threadIdx.x >> 6;
  int lane = threadIdx.x & 63;
  int t = blockIdx.x * 4 + wave;

  const float4* xr = (const float4*)(x + (size_t)t * DDIM + lane * 16);
  float xv[16];
  float4 q0 = xr[0], q1 = xr[1], q2 = xr[2], q3 = xr[3];
  xv[0]=q0.x; xv[1]=q0.y; xv[2]=q0.z; xv[3]=q0.w;
  xv[4]=q1.x; xv[5]=q1.y; xv[6]=q1.z; xv[7]=q1.w;
  xv[8]=q2.x; xv[9]=q2.y; xv[10]=q2.z; xv[11]=q2.w;
  xv[12]=q3.x; xv[13]=q3.y; xv[14]=q3.z; xv[15]=q3.w;

  float acc[8];
#pragma unroll
  for (int e = 0; e < 8; ++e) acc[e] = 0.f;
  const float* gwr = gw + (size_t)lane * 16 * 8;
#pragma unroll
  for (int j = 0; j < 16; ++j) {
    const float4* g = (const float4*)(gwr + j * 8);
    float4 g0 = g[0], g1 = g[1];
    float xj = xv[j];
    acc[0] += xj * g0.x; acc[1] += xj * g0.y;
    acc[2] += xj * g0.z; acc[3] += xj * g0.w;
    acc[4] += xj * g1.x; acc[5] += xj * g1.y;
    acc[6] += xj * g1.z; acc[7] += xj * g1.w;
  }
#pragma unroll
  for (int off = 32; off > 0; off >>= 1) {
#pragma unroll
    for (int e = 0; e < 8; ++e) acc[e] += __shfl_xor(acc[e], off, 64);
  }
  if (lane == 0) {
    float logit[8], m = -1e30f;
#pragma unroll
    for (int e = 0; e < 8; ++e) { logit[e] = acc[e] + gb[e]; m = fmaxf(m, logit[e]); }
    float p[8], s = 0.f;
#pragma unroll
    for (int e = 0; e < 8; ++e) { p[e] = expf(logit[e] - m); s += p[e]; }
    float wv[8], wsum = 0.f;
#pragma unroll
    for (int e = 0; e < 8; ++e) {
      float pr = p[e] / s;
      wv[e] = (pr >= 0.1f) ? pr : 0.f;
      wsum += wv[e];
    }
    float invw = (wsum == 0.f) ? 1.f : (1.f / wsum);
#pragma unroll
    for (int e = 0; e < 8; ++e) wout[(size_t)t * 8 + e] = wv[e] * invw;
  }

  // bf16 pack + swizzled chunk store (lane covers k = lane*16 .. +15)
  int r   = t & 15, m16 = t >> 4;
  int rot = ((r >> 1) & 3) * 8;
  int k32 = lane >> 1;
  int kb  = (lane & 1) * 16;
  unsigned short* chunk = xt + ((((size_t)m16 * 32) + k32) << 9) + r * 32;
  uint4 p0, p1;
  p0.x = pack2(xv[0],  xv[1]);  p0.y = pack2(xv[2],  xv[3]);
  p0.z = pack2(xv[4],  xv[5]);  p0.w = pack2(xv[6],  xv[7]);
  p1.x = pack2(xv[8],  xv[9]);  p1.y = pack2(xv[10], xv[11]);
  p1.z = pack2(xv[12], xv[13]); p1.w = pack2(xv[14], xv[15]);
  *(uint4*)(chunk + (kb ^ rot))       = p0;
  *(uint4*)(chunk + ((kb + 8) ^ rot)) = p1;
}

// ---------------------------------------------------------------------------
// Kernel 2: expert_w fp32 [e][k][d] -> Bt bf16 chunk-tiled
// [e][d/16][k/32][16][32] with the same XOR swizzle (transpose via LDS tile).
// ---------------------------------------------------------------------------
__global__ __launch_bounds__(256) void prep_w(
    const float* __restrict__ ew, unsigned short* __restrict__ bt) {
  __shared__ float tile[32][33];
  int e  = blockIdx.z;
  int k0 = blockIdx.y * 32;
  int d0 = blockIdx.x * 32;
  int c4 = threadIdx.x & 7;
  int r  = threadIdx.x >> 3;

  const float* src = ew + ((size_t)e << 20) + (size_t)(k0 + r) * DDIM + d0 + c4 * 4;
  float4 v = *(const float4*)src;
  tile[r][c4 * 4 + 0] = v.x;
  tile[r][c4 * 4 + 1] = v.y;
  tile[r][c4 * 4 + 2] = v.z;
  tile[r][c4 * 4 + 3] = v.w;
  __syncthreads();

  uint2 pk;
  pk.x = pack2(tile[c4 * 4 + 0][r], tile[c4 * 4 + 1][r]);
  pk.y = pack2(tile[c4 * 4 + 2][r], tile[c4 * 4 + 3][r]);
  int d   = d0 + r;                  // output row (n), cols k = k0+c4*4 .. +3
  int d16 = d >> 4, r16 = d & 15, k32 = k0 >> 5, kc = c4 * 4;
  int rot = ((r16 >> 1) & 3) * 8;
  *(uint2*)(bt + ((((size_t)e * 64 + d16) * 32 + k32) << 9) + r16 * 32 + (kc ^ rot)) = pk;
}

// ---------------------------------------------------------------------------
// Kernel 3: MoE GEMM, m97 structure, single accumulator via Horner w-folding:
// invariant after expert e: coeff of G_j in acc = w'_j / w'_e (w' = max(w,eps)).
// Boundary: acc *= w'_e / w'_{e+1}.  Epilogue: out = acc * w'_7 + sum_e w_e*b_e.
// Pure-DMA bf16 K-loop (global_load_lds width 16), swizzled frag reads.
// ---------------------------------------------------------------------------
__global__ __launch_bounds__(256, 4) void moe_gemm(
    const unsigned short* __restrict__ xt,  // [1024][32][16][32] bf16 swizzled
    const float* __restrict__ w,            // [16384][8]
    const unsigned short* __restrict__ bt,  // [8][64][32][16][32] bf16 swizzled
    const float* __restrict__ eb, float* __restrict__ out) {
  __shared__ unsigned short As[8 * 512];  // 8 chunks x 1 KB
  __shared__ unsigned short Bs[8 * 512];

  int tid  = threadIdx.x;
  int wave = tid >> 6;
  int lane = tid & 63;
  int bn0  = blockIdx.x * BN;
  int bm0  = blockIdx.y * BM;
  int wm   = (wave >> 1) * 64;
  int wn   = (wave & 1) * 64;
  int fr   = lane & 15;
  int q8   = (lane >> 4) * 8;
  int cr0  = (lane >> 4) * 4;

  int rotf = ((fr >> 1) & 3) * 8;
  int qel  = fr * 32 + (q8 ^ rotf);   // swizzled element offset within chunk

  const int bm16 = bm0 >> 4;
  const int bn16 = bn0 >> 4;
  const int tb   = bm0 + wm + cr0;    // this lane's token base (rows tb+mi*16+r)

  floatx4 acc[4][4];
#pragma unroll
  for (int mi = 0; mi < 4; ++mi)
#pragma unroll
    for (int ni = 0; ni < 4; ++ni) acc[mi][ni] = (floatx4)0.f;

  for (int e = 0; e < 8; ++e) {
    const unsigned short* bbase = bt + (((size_t)e * 2048) << 9);
    for (int kt = 0; kt < 32; ++kt) {
      __syncthreads();  // prior frag reads complete before LDS overwrite
#pragma unroll
      for (int j = 0; j < 2; ++j) {
        int c = wave * 2 + j;
        const unsigned short* gpa =
            xt + ((((size_t)(bm16 + c)) * 32 + kt) << 9) + lane * 8;
        __builtin_amdgcn_global_load_lds(
            (const __attribute__((address_space(1))) unsigned int*)gpa,
            (__attribute__((address_space(3))) unsigned int*)(As + c * 512), 16, 0, 0);
        const unsigned short* gpb =
            bbase + ((((size_t)(bn16 + c)) * 32 + kt) << 9) + lane * 8;
        __builtin_amdgcn_global_load_lds(
            (const __attribute__((address_space(1))) unsigned int*)gpb,
            (__attribute__((address_space(3))) unsigned int*)(Bs + c * 512), 16, 0, 0);
      }
      __syncthreads();  // staged data visible

      short8 af[4], bfr[4];
#pragma unroll
      for (int mi = 0; mi < 4; ++mi)
        af[mi] = *(const short8*)&As[((((wm >> 4) + mi)) << 9) + qel];
#pragma unroll
      for (int ni = 0; ni < 4; ++ni)
        bfr[ni] = *(const short8*)&Bs[((((wn >> 4) + ni)) << 9) + qel];
#pragma unroll
      for (int mi = 0; mi < 4; ++mi)
#pragma unroll
        for (int ni = 0; ni < 4; ++ni)
          acc[mi][ni] = __builtin_amdgcn_mfma_f32_16x16x32_bf16(
              af[mi], bfr[ni], acc[mi][ni], 0, 0, 0);
    }
    // Horner boundary: acc *= w'_e / w'_{e+1}, per token row
    if (e < 7) {
#pragma unroll
      for (int mi = 0; mi < 4; ++mi)
#pragma unroll
        for (int r = 0; r < 4; ++r) {
          int t = tb + mi * 16 + r;
          float wc = fmaxf(w[(size_t)t * 8 + e],     WEPS);
          float wx = fmaxf(w[(size_t)t * 8 + e + 1], WEPS);
          float ratio = wc * __builtin_amdgcn_rcpf(wx);
#pragma unroll
          for (int ni = 0; ni < 4; ++ni) acc[mi][ni][r] *= ratio;
        }
    }
  }

  // ---- epilogue: out = acc * w'_7 + sum_e w_e * eb_e ----
  float ebv[8][4];
#pragma unroll
  for (int e = 0; e < 8; ++e)
#pragma unroll
    for (int ni = 0; ni < 4; ++ni)
      ebv[e][ni] = eb[(size_t)e * DDIM + bn0 + wn + ni * 16 + fr];

#pragma unroll
  for (int mi = 0; mi < 4; ++mi) {
#pragma unroll
    for (int r = 0; r < 4; ++r) {
      int t = tb + mi * 16 + r;
      const float4* wp = (const float4*)(w + (size_t)t * 8);
      float4 w0 = wp[0];
      float4 w1 = wp[1];
      float w7 = fmaxf(w1.w, WEPS);   // final Horner scale
      float* orow = out + (size_t)t * DDIM + bn0 + wn + fr;
#pragma unroll
      for (int ni = 0; ni < 4; ++ni) {
        float bias = w0.x * ebv[0][ni] + w0.y * ebv[1][ni] +
                     w0.z * ebv[2][ni] + w0.w * ebv[3][ni] +
                     w1.x * ebv[4][ni] + w1.y * ebv[5][ni] +
                     w1.z * ebv[6][ni] + w1.w * ebv[7][ni];
        orow[ni * 16] = acc[mi][ni][r] * w7 + bias;
      }
    }
  }
}

// ---------------------------------------------------------------------------
extern "C" void kernel_launch(void* const* d_in, const int* in_sizes, int n_in,
                              void* d_out, int out_size, void* d_ws, size_t ws_size,
                              hipStream_t stream) {
  const float* x  = (const float*)d_in[0];   // [4,4096,1024]
  const float* gw = (const float*)d_in[1];   // [1024,8]
  const float* gb = (const float*)d_in[2];   // [8]
  const float* ew = (const float*)d_in[3];   // [8,1024,1024]
  const float* eb = (const float*)d_in[4];   // [8,1024]
  float* out = (float*)d_out;

  // ws: w[16384*8] fp32 (512 KB) | Xt bf16 (32 MB) | Bt bf16 (16 MB)
  float* wbuf = (float*)d_ws;
  unsigned short* xt = (unsigned short*)((char*)d_ws + (size_t)TOK * 8 * 4);
  unsigned short* bt = xt + (size_t)TOK * DDIM;

  gate_prep<<<TOK / 4, 256, 0, stream>>>(x, gw, gb, wbuf, xt);
  prep_w<<<dim3(DDIM / 32, DDIM / 32, NEXP), 256, 0, stream>>>(ew, bt);
  moe_gemm<<<dim3(DDIM / BN, TOK / BM), 256, 0, stream>>>(xt, wbuf, bt, eb, out);
}

// Round 5
// 534.204 us; speedup vs baseline: 1.4976x; 1.0118x over previous
//
#include <hip/hip_runtime.h>
#include <stdint.h>

#define TOK   16384
#define DDIM  1024
#define NEXP  8
#define BM    128
#define BN    128
#define WEPS  1e-5f

typedef __attribute__((ext_vector_type(8))) short  short8;
typedef __attribute__((ext_vector_type(4))) float  floatx4;

// round-to-nearest-even f32 -> bf16 (normal-range data; no NaN path needed)
static __device__ __forceinline__ unsigned int bf16_rne(float f) {
  unsigned int u = __builtin_bit_cast(unsigned int, f);
  return (u + 0x7fffu + ((u >> 16) & 1u)) >> 16;
}
static __device__ __forceinline__ unsigned int pack2(float a, float b) {
  return bf16_rne(a) | (bf16_rne(b) << 16);
}

// ---------------------------------------------------------------------------
// Kernel 1: fp32 gate (w only). One wave per token, coalesced x reads.
// w[t][8] = renormalized thresholded softmax(x@gw+gb). fp32 throughout so
// selection decisions (>= 0.1) match the fp32 reference.
// ---------------------------------------------------------------------------
__global__ __launch_bounds__(256) void gate_kernel(
    const float* __restrict__ x, const float* __restrict__ gw,
    const float* __restrict__ gb, float* __restrict__ wout) {
  int wave = threadIdx.x >> 6;
  int lane = threadIdx.x & 63;
  int t = blockIdx.x * 4 + wave;
  const float* xr = x + (size_t)t * DDIM;

  float acc[8];
#pragma unroll
  for (int e = 0; e < 8; ++e) acc[e] = 0.f;

#pragma unroll
  for (int i = 0; i < DDIM / 64; ++i) {
    int k = lane + 64 * i;
    float xv = xr[k];
    const float4* g = (const float4*)(gw + (size_t)k * 8);
    float4 g0 = g[0];
    float4 g1 = g[1];
    acc[0] += xv * g0.x; acc[1] += xv * g0.y;
    acc[2] += xv * g0.z; acc[3] += xv * g0.w;
    acc[4] += xv * g1.x; acc[5] += xv * g1.y;
    acc[6] += xv * g1.z; acc[7] += xv * g1.w;
  }
#pragma unroll
  for (int off = 32; off > 0; off >>= 1) {
#pragma unroll
    for (int e = 0; e < 8; ++e) acc[e] += __shfl_xor(acc[e], off, 64);
  }
  if (lane == 0) {
    float logit[8], m = -1e30f;
#pragma unroll
    for (int e = 0; e < 8; ++e) { logit[e] = acc[e] + gb[e]; m = fmaxf(m, logit[e]); }
    float p[8], s = 0.f;
#pragma unroll
    for (int e = 0; e < 8; ++e) { p[e] = expf(logit[e] - m); s += p[e]; }
    float wv[8], wsum = 0.f;
#pragma unroll
    for (int e = 0; e < 8; ++e) {
      float pr = p[e] / s;
      wv[e] = (pr >= 0.1f) ? pr : 0.f;
      wsum += wv[e];
    }
    float invw = (wsum == 0.f) ? 1.f : (1.f / wsum);
#pragma unroll
    for (int e = 0; e < 8; ++e) wout[(size_t)t * 8 + e] = wv[e] * invw;
  }
}

// ---------------------------------------------------------------------------
// Kernel 2: x fp32 [t][k] -> Xt bf16 chunk-tiled [t/16][k/32][16][32] with XOR
// bank swizzle (element (r,c) at r*32 + (c ^ (((r>>1)&3)*8))). One wave per
// 1 KB chunk: reads 128-B row quads, writes one coalesced 1 KB chunk.
// ---------------------------------------------------------------------------
__global__ __launch_bounds__(256) void prep_x(
    const float* __restrict__ x, unsigned short* __restrict__ xt) {
  int g    = blockIdx.x * 4 + (threadIdx.x >> 6);  // chunk id
  int lane = threadIdx.x & 63;
  int m16 = g >> 5, k32 = g & 31;
  int r  = lane >> 2;        // token row within chunk
  int c4 = lane & 3;         // 8-element col group

  const float* src = x + (size_t)(m16 * 16 + r) * DDIM + k32 * 32 + c4 * 8;
  float4 v0 = *(const float4*)src;
  float4 v1 = *(const float4*)(src + 4);
  uint4 pk;
  pk.x = pack2(v0.x, v0.y); pk.y = pack2(v0.z, v0.w);
  pk.z = pack2(v1.x, v1.y); pk.w = pack2(v1.z, v1.w);
  int rot = ((r >> 1) & 3) * 8;
  *(uint4*)(xt + ((size_t)g << 9) + r * 32 + ((c4 * 8) ^ rot)) = pk;
}

// ---------------------------------------------------------------------------
// Kernel 3: expert_w fp32 [e][k][d] -> Bt bf16 chunk-tiled
// [e][d/16][k/32][16][32] with the same XOR swizzle (transpose via LDS tile).
// ---------------------------------------------------------------------------
__global__ __launch_bounds__(256) void prep_w(
    const float* __restrict__ ew, unsigned short* __restrict__ bt) {
  __shared__ float tile[32][33];
  int e  = blockIdx.z;
  int k0 = blockIdx.y * 32;
  int d0 = blockIdx.x * 32;
  int c4 = threadIdx.x & 7;
  int r  = threadIdx.x >> 3;

  const float* src = ew + ((size_t)e << 20) + (size_t)(k0 + r) * DDIM + d0 + c4 * 4;
  float4 v = *(const float4*)src;
  tile[r][c4 * 4 + 0] = v.x;
  tile[r][c4 * 4 + 1] = v.y;
  tile[r][c4 * 4 + 2] = v.z;
  tile[r][c4 * 4 + 3] = v.w;
  __syncthreads();

  uint2 pk;
  pk.x = pack2(tile[c4 * 4 + 0][r], tile[c4 * 4 + 1][r]);
  pk.y = pack2(tile[c4 * 4 + 2][r], tile[c4 * 4 + 3][r]);
  int d   = d0 + r;                  // output row (n), cols k = k0+c4*4 .. +3
  int d16 = d >> 4, r16 = d & 15, k32 = k0 >> 5, kc = c4 * 4;
  int rot = ((r16 >> 1) & 3) * 8;
  *(uint2*)(bt + ((((size_t)e * 64 + d16) * 32 + k32) << 9) + r16 * 32 + (kc ^ rot)) = pk;
}

// ---------------------------------------------------------------------------
// Kernel 4: MoE GEMM. m97 structure, BK=64 (32 MFMA per barrier pair), single
// accumulator via Horner w-folding: after expert e, coeff of G_j = w'_j/w'_e
// (w' = max(w,eps)); boundary acc *= w'_e/w'_{e+1}; epilogue *= w'_7 + bias.
// Pure-DMA bf16 K-loop: global_load_lds width 16, swizzled conflict-free frags.
// ---------------------------------------------------------------------------
__global__ __launch_bounds__(256, 4) void moe_gemm(
    const unsigned short* __restrict__ xt,  // [1024][32][16][32] bf16 swizzled
    const float* __restrict__ w,            // [16384][8]
    const unsigned short* __restrict__ bt,  // [8][64][32][16][32] bf16 swizzled
    const float* __restrict__ eb, float* __restrict__ out) {
  __shared__ unsigned short As[16 * 512];  // 16 chunks x 1 KB (BK=64)
  __shared__ unsigned short Bs[16 * 512];

  int tid  = threadIdx.x;
  int wave = tid >> 6;
  int lane = tid & 63;
  int bn0  = blockIdx.x * BN;   // bn fastest: XCD = linear%8 = bn -> B slice L2-resident
  int bm0  = blockIdx.y * BM;
  int wm   = (wave >> 1) * 64;
  int wn   = (wave & 1) * 64;
  int fr   = lane & 15;
  int q8   = (lane >> 4) * 8;
  int cr0  = (lane >> 4) * 4;

  int rotf = ((fr >> 1) & 3) * 8;
  int qel  = fr * 32 + (q8 ^ rotf);   // swizzled element offset within chunk

  const int bm16 = bm0 >> 4;
  const int bn16 = bn0 >> 4;
  const int tb   = bm0 + wm + cr0;

  floatx4 acc[4][4];
#pragma unroll
  for (int mi = 0; mi < 4; ++mi)
#pragma unroll
    for (int ni = 0; ni < 4; ++ni) acc[mi][ni] = (floatx4)0.f;

  for (int e = 0; e < 8; ++e) {
    const unsigned short* bbase = bt + (((size_t)e * 2048) << 9);
    for (int s = 0; s < 16; ++s) {   // 16 stages x BK=64
      __syncthreads();  // prior frag reads complete before LDS overwrite
#pragma unroll
      for (int j = 0; j < 2; ++j) {
        int c = wave * 2 + j;        // m/n chunk row 0..7
#pragma unroll
        for (int ks = 0; ks < 2; ++ks) {
          int kt = s * 2 + ks;
          const unsigned short* gpa =
              xt + ((((size_t)(bm16 + c)) * 32 + kt) << 9) + lane * 8;
          __builtin_amdgcn_global_load_lds(
              (const __attribute__((address_space(1))) unsigned int*)gpa,
              (__attribute__((address_space(3))) unsigned int*)(As + (c * 2 + ks) * 512),
              16, 0, 0);
          const unsigned short* gpb =
              bbase + ((((size_t)(bn16 + c)) * 32 + kt) << 9) + lane * 8;
          __builtin_amdgcn_global_load_lds(
              (const __attribute__((address_space(1))) unsigned int*)gpb,
              (__attribute__((address_space(3))) unsigned int*)(Bs + (c * 2 + ks) * 512),
              16, 0, 0);
        }
      }
      __syncthreads();  // staged data visible

#pragma unroll
      for (int ks = 0; ks < 2; ++ks) {   // two half-stages keep live regs low
        short8 af[4], bfr[4];
#pragma unroll
        for (int mi = 0; mi < 4; ++mi)
          af[mi] = *(const short8*)&As[((((wm >> 4) + mi) * 2 + ks) << 9) + qel];
#pragma unroll
        for (int ni = 0; ni < 4; ++ni)
          bfr[ni] = *(const short8*)&Bs[((((wn >> 4) + ni) * 2 + ks) << 9) + qel];
#pragma unroll
        for (int mi = 0; mi < 4; ++mi)
#pragma unroll
          for (int ni = 0; ni < 4; ++ni)
            acc[mi][ni] = __builtin_amdgcn_mfma_f32_16x16x32_bf16(
                af[mi], bfr[ni], acc[mi][ni], 0, 0, 0);
      }
    }
    // Horner boundary: acc *= w'_e / w'_{e+1}, per token row
    if (e < 7) {
#pragma unroll
      for (int mi = 0; mi < 4; ++mi)
#pragma unroll
        for (int r = 0; r < 4; ++r) {
          int t = tb + mi * 16 + r;
          float wc = fmaxf(w[(size_t)t * 8 + e],     WEPS);
          float wx = fmaxf(w[(size_t)t * 8 + e + 1], WEPS);
          float ratio = wc * __builtin_amdgcn_rcpf(wx);
#pragma unroll
          for (int ni = 0; ni < 4; ++ni) acc[mi][ni][r] *= ratio;
        }
    }
  }

  // ---- epilogue: out = acc * w'_7 + sum_e w_e * eb_e ----
  float ebv[8][4];
#pragma unroll
  for (int e = 0; e < 8; ++e)
#pragma unroll
    for (int ni = 0; ni < 4; ++ni)
      ebv[e][ni] = eb[(size_t)e * DDIM + bn0 + wn + ni * 16 + fr];

#pragma unroll
  for (int mi = 0; mi < 4; ++mi) {
#pragma unroll
    for (int r = 0; r < 4; ++r) {
      int t = tb + mi * 16 + r;
      const float4* wp = (const float4*)(w + (size_t)t * 8);
      float4 w0 = wp[0];
      float4 w1 = wp[1];
      float w7 = fmaxf(w1.w, WEPS);   // final Horner scale
      float* orow = out + (size_t)t * DDIM + bn0 + wn + fr;
#pragma unroll
      for (int ni = 0; ni < 4; ++ni) {
        float bias = w0.x * ebv[0][ni] + w0.y * ebv[1][ni] +
                     w0.z * ebv[2][ni] + w0.w * ebv[3][ni] +
                     w1.x * ebv[4][ni] + w1.y * ebv[5][ni] +
                     w1.z * ebv[6][ni] + w1.w * ebv[7][ni];
        orow[ni * 16] = acc[mi][ni][r] * w7 + bias;
      }
    }
  }
}

// ---------------------------------------------------------------------------
extern "C" void kernel_launch(void* const* d_in, const int* in_sizes, int n_in,
                              void* d_out, int out_size, void* d_ws, size_t ws_size,
                              hipStream_t stream) {
  const float* x  = (const float*)d_in[0];   // [4,4096,1024]
  const float* gw = (const float*)d_in[1];   // [1024,8]
  const float* gb = (const float*)d_in[2];   // [8]
  const float* ew = (const float*)d_in[3];   // [8,1024,1024]
  const float* eb = (const float*)d_in[4];   // [8,1024]
  float* out = (float*)d_out;

  // ws: w[16384*8] fp32 (512 KB) | Xt bf16 (32 MB) | Bt bf16 (16 MB)
  float* wbuf = (float*)d_ws;
  unsigned short* xt = (unsigned short*)((char*)d_ws + (size_t)TOK * 8 * 4);
  unsigned short* bt = xt + (size_t)TOK * DDIM;

  gate_kernel<<<TOK / 4, 256, 0, stream>>>(x, gw, gb, wbuf);
  prep_x<<<(TOK / 16) * 32 / 4, 256, 0, stream>>>(x, xt);
  prep_w<<<dim3(DDIM / 32, DDIM / 32, NEXP), 256, 0, stream>>>(ew, bt);
  moe_gemm<<<dim3(DDIM / BN, TOK / BM), 256, 0, stream>>>(xt, wbuf, bt, eb, out);
}